// Round 14
// baseline (110.642 us; speedup 1.0000x reference)
//
#include <hip/hip_runtime.h>

#define HH 1024
#define WW 1024
#define KK 9
#define PADK 4
#define TSX 16
#define TSY 16      // block = 16x16 px, 128 threads, 2 px/thread
#define TROWS 24    // TSY + 2*PADK
#define TCOLS 24
#define TSTR 25     // float4 row stride
#define NW 81
#define ROWB 5184   // 16 px * 324 B contiguous per image row
#define SLOTF 5184  // floats per wave slot (4 rows * 16 px * 81)

#define GLDS(src, dst, w)                                              \
  __builtin_amdgcn_global_load_lds(                                    \
      (const __attribute__((address_space(1))) unsigned int*)(src),    \
      (__attribute__((address_space(3))) unsigned int*)(dst), w, 0, 0)

#define SBAR __builtin_amdgcn_sched_barrier(0)

// Long-phase depth-2 pipeline. Thread owns 2 px (rows ty, ty+8). Per wave:
// 48 DMA ops (chunk A = its first 4 weight-rows, chunk B = its second 4)
// issued up front into its own slot halves; vmcnt(24) starts phase-A compute
// with chunk B's 24 ops riding across the whole ~2000-cyc phase; vmcnt(0)
// then phase B. Results held in regs, stored at the end -> exact counts.
// No weight barriers (own-wave data only); one raw s_barrier for the tile.
// LDS 51 KB -> 3 blocks/CU (same occupancy as R12: isolates the pipeline).
__global__ __launch_bounds__(128) void denoiser_kpn(
    const float* __restrict__ unet, const float* __restrict__ cnn,
    float* __restrict__ out) {
  __shared__ __attribute__((aligned(16))) float wlds[2][2][SLOTF];  // [wave][phase] 41.5 KB
  __shared__ float4 tile[TROWS][TSTR];                              // 9600 B

  const int tid = threadIdx.x;
  const int lane = tid & 63;
  const int wv = tid >> 6;
  const int tx = tid & 15;
  const int ty = tid >> 4;  // 0..7
  const int px0 = blockIdx.x * TSX;
  const int py0 = blockIdx.y * TSY;

  // ---- 1. Tile global loads (oldest VMEM): 576 entries over 128 thr. ----
  float tr_[5][3];
#pragma unroll
  for (int i = 0; i < 5; ++i) {
    int e = tid + 128 * i;
    if (e > 575) e = 575;  // dup load; ds_write predicated
    const int r = e / TCOLS;
    const int c = e - r * TCOLS;
    int gy = py0 - PADK + r;
    gy = gy < 0 ? -gy : (gy >= HH ? 2 * HH - 2 - gy : gy);
    int gx = px0 - PADK + c;
    gx = gx < 0 ? -gx : (gx >= WW ? 2 * WW - 2 - gx : gx);
    __builtin_memcpy(&tr_[i][0], unet + ((size_t)gy * WW + gx) * 3, 12);
  }
  SBAR;

  // ---- 2. Both chunks' DMA up front: 2 x 4 rows x 6 ops = 48 per wave.
  //         Chunk (wv, ph) = image rows py0 + ph*8 + wv*4 + r. ----
#pragma unroll
  for (int ph = 0; ph < 2; ++ph)
#pragma unroll
    for (int r = 0; r < 4; ++r) {
      const int gr = py0 + ph * 8 + wv * 4 + r;
      const char* s = (const char*)(cnn + ((size_t)gr * WW + px0) * NW);
      char* d = (char*)&wlds[wv][ph][0] + r * ROWB;
#pragma unroll
      for (int i = 0; i < 5; ++i)
        GLDS(s + i * 1024 + lane * 16, d + i * 1024 + lane * 16, 16);
      if (lane < 4) GLDS(s + 5120 + lane * 16, d + 5120 + lane * 16, 16);
    }
  SBAR;

  // ---- 3. Tile -> LDS (compiler waits the 5 tile loads, vmcnt(48)). ----
#pragma unroll
  for (int i = 0; i < 5; ++i) {
    const int idx = tid + 128 * i;
    if (idx < 576) {
      const int r = idx / TCOLS;
      const int c = idx - r * TCOLS;
      tile[r][c] = make_float4(tr_[i][0], tr_[i][1], tr_[i][2], 0.0f);
    }
  }
  SBAR;
  asm volatile("s_waitcnt lgkmcnt(0)" ::: "memory");
  __builtin_amdgcn_s_barrier();  // publish tile; 48 DMA ops stay in flight
  SBAR;

  const float* wrow = &wlds[wv][0][lane * NW];  // lane = (ty&3)*16+tx

  // ---- 4. Phase A: chunk A ready, chunk B (newest 24) rides. ----
  asm volatile("s_waitcnt vmcnt(24)" ::: "memory");
  SBAR;
  float a0 = 0.f, a1 = 0.f, a2 = 0.f;
#pragma unroll
  for (int ki = 0; ki < KK; ++ki)
#pragma unroll
    for (int kj = 0; kj < KK; ++kj) {
      const float4 pv = tile[ty + ki][tx + kj];
      const float w = wrow[ki * KK + kj];
      a0 = fmaf(w, pv.x, a0);
      a1 = fmaf(w, pv.y, a1);
      a2 = fmaf(w, pv.z, a2);
    }
  SBAR;

  // ---- 5. Phase B: drain chunk B (nothing else outstanding). ----
  asm volatile("s_waitcnt vmcnt(0)" ::: "memory");
  SBAR;
  const float* wrowB = &wlds[wv][1][lane * NW];
  float b0 = 0.f, b1 = 0.f, b2 = 0.f;
#pragma unroll
  for (int ki = 0; ki < KK; ++ki)
#pragma unroll
    for (int kj = 0; kj < KK; ++kj) {
      const float4 pv = tile[8 + ty + ki][tx + kj];
      const float w = wrowB[ki * KK + kj];
      b0 = fmaf(w, pv.x, b0);
      b1 = fmaf(w, pv.y, b1);
      b2 = fmaf(w, pv.z, b2);
    }

  // ---- 6. Stores (after all counted waits). ----
  const float oa[3] = {a0, a1, a2};
  const float ob[3] = {b0, b1, b2};
  __builtin_memcpy(out + ((size_t)(py0 + ty) * WW + px0 + tx) * 3, &oa[0], 12);
  __builtin_memcpy(out + ((size_t)(py0 + 8 + ty) * WW + px0 + tx) * 3, &ob[0], 12);
}

extern "C" void kernel_launch(void* const* d_in, const int* in_sizes, int n_in,
                              void* d_out, int out_size, void* d_ws, size_t ws_size,
                              hipStream_t stream) {
  const float* unet = (const float*)d_in[0];  // [1024,1024,3] f32
  const float* cnn = (const float*)d_in[1];   // [1024,1024,81] f32
  float* out = (float*)d_out;                 // [1024,1024,3] f32
  dim3 grid(WW / TSX, HH / TSY);              // 64 x 64 = 4096 blocks
  dim3 block(128);
  denoiser_kpn<<<grid, block, 0, stream>>>(unet, cnn, out);
}

// Round 15
// 76.554 us; speedup vs baseline: 1.4453x; 1.4453x over previous
//
#include <hip/hip_runtime.h>

#define HH 1024
#define WW 1024
#define KK 9
#define PADK 4
#define TSX 16
#define TSY 8
#define TROWS 16    // TSY + 2*PADK
#define TCOLS 24    // TSX + 2*PADK
#define TSTR 25     // float4 row stride
#define NW 81
#define ROWB 5184   // 16 px * 324 B contiguous per image row
#define CHUNKF 2592 // chunk = 2 rows * 16 px * 81 floats = 10368 B

#define GLDS(src, dst, w)                                              \
  __builtin_amdgcn_global_load_lds(                                    \
      (const __attribute__((address_space(1))) unsigned int*)(src),    \
      (__attribute__((address_space(3))) unsigned int*)(dst), w, 0, 0)

#define SBAR __builtin_amdgcn_sched_barrier(0)

// R12's footprint (16x8 px, 128 thr, 48 KB LDS, 3 blocks/CU, single-pass
// weights) with ONE change: each wave's weight wait is split depth-2.
// Wave wv owns rows wv*4..wv*4+3, staged as chunk0 (rows 0,1) + chunk1
// (rows 2,3), 12 DMA ops each. vmcnt(12) -> compute chunk0 (32 px,
// 2 thr/px, k split by kernel-row 36/45 -> compile-time offsets) while
// chunk1's 10.4 KB rides; vmcnt(0) -> chunk1. Halves the post-barrier
// exposed DMA latency that R12 left serial. (R14 was an invalid test:
// 16x16 needs 83 KB weights -> 1 block/CU occupancy collapse.)
__global__ __launch_bounds__(128) void denoiser_kpn(
    const float* __restrict__ unet, const float* __restrict__ cnn,
    float* __restrict__ out) {
  __shared__ __attribute__((aligned(16))) float wlds[2][2][CHUNKF];  // 41472 B
  __shared__ float4 tile[TROWS][TSTR];                               // 6400 B

  const int tid = threadIdx.x;
  const int lane = tid & 63;
  const int wv = tid >> 6;   // wave 0/1
  const int p = lane >> 1;   // chunk-pixel 0..31
  const int h = lane & 1;    // k-half: 0 -> ki 0..3 (36 taps), 1 -> ki 4..8 (45)
  const int px0 = blockIdx.x * TSX;
  const int py0 = blockIdx.y * TSY;

  // ---- 1. Tile global loads first (oldest VMEM): 384 entries / 128 thr. ----
  float tr_[3][3];
#pragma unroll
  for (int i = 0; i < 3; ++i) {
    const int idx = tid + 128 * i;  // 0..383 over 16x24
    const int r = idx / TCOLS;
    const int c = idx - r * TCOLS;
    int gy = py0 - PADK + r;
    gy = gy < 0 ? -gy : (gy >= HH ? 2 * HH - 2 - gy : gy);
    int gx = px0 - PADK + c;
    gx = gx < 0 ? -gx : (gx >= WW ? 2 * WW - 2 - gx : gx);
    __builtin_memcpy(&tr_[i][0], unet + ((size_t)gy * WW + gx) * 3, 12);
  }
  SBAR;

  // ---- 2. Weight DMA: 2 chunks x 2 rows x 6 ops = 24 per wave, own rows. --
#pragma unroll
  for (int c = 0; c < 2; ++c)
#pragma unroll
    for (int r = 0; r < 2; ++r) {
      const int gr = py0 + wv * 4 + c * 2 + r;
      const char* s = (const char*)(cnn + ((size_t)gr * WW + px0) * NW);
      char* d = (char*)&wlds[wv][c][0] + r * ROWB;
#pragma unroll
      for (int i = 0; i < 5; ++i)
        GLDS(s + i * 1024 + lane * 16, d + i * 1024 + lane * 16, 16);
      if (lane < 4) GLDS(s + 5120 + lane * 16, d + 5120 + lane * 16, 16);
    }
  SBAR;

  // ---- 3. Tile -> LDS (compiler waits only the 3 tile loads: vmcnt(24)). --
#pragma unroll
  for (int i = 0; i < 3; ++i) {
    const int idx = tid + 128 * i;
    const int r = idx / TCOLS;
    const int c = idx - r * TCOLS;
    tile[r][c] = make_float4(tr_[i][0], tr_[i][1], tr_[i][2], 0.0f);
  }
  SBAR;
  asm volatile("s_waitcnt lgkmcnt(0)" ::: "memory");
  __builtin_amdgcn_s_barrier();  // publish tile; 24 DMA ops stay in flight
  SBAR;

  const int bcol = p & 15;
  const int r0 = p >> 4;  // row within chunk (0/1)

  // Compute one chunk: 32 px, 2 thr/px, taps ki = n/9 (+4 if h), kj = n%9 --
  // all tile/weight offsets compile-time (imm ds_read). Reduce via shfl(1).
  auto do_chunk = [&](int c) {
    const int brow = wv * 4 + c * 2 + r0;
    const float* wb = &wlds[wv][c][p * NW + 36 * h];
    const int tb = brow + (h ? 4 : 0);
    float ax = 0.f, ay = 0.f, az = 0.f;
#pragma unroll
    for (int n = 0; n < 45; ++n) {
      if (n < 36 || h) {
        const float4 pv = tile[tb + n / 9][bcol + n % 9];
        const float w = wb[n];
        ax = fmaf(w, pv.x, ax);
        ay = fmaf(w, pv.y, ay);
        az = fmaf(w, pv.z, az);
      }
    }
    ax += __shfl_xor(ax, 1);
    ay += __shfl_xor(ay, 1);
    az += __shfl_xor(az, 1);
    if (h == 0) {
      const float o[3] = {ax, ay, az};
      __builtin_memcpy(out + ((size_t)(py0 + brow) * WW + px0 + bcol) * 3,
                       &o[0], 12);
    }
  };

  // ---- 4. Phase A: chunk0 ready when <=12 outstanding (chunk1 rides). ----
  asm volatile("s_waitcnt vmcnt(12)" ::: "memory");
  SBAR;
  do_chunk(0);
  SBAR;
  // ---- 5. Phase B: chunk1 landed. ----
  asm volatile("s_waitcnt vmcnt(0)" ::: "memory");
  SBAR;
  do_chunk(1);
}

extern "C" void kernel_launch(void* const* d_in, const int* in_sizes, int n_in,
                              void* d_out, int out_size, void* d_ws, size_t ws_size,
                              hipStream_t stream) {
  const float* unet = (const float*)d_in[0];  // [1024,1024,3] f32
  const float* cnn = (const float*)d_in[1];   // [1024,1024,81] f32
  float* out = (float*)d_out;                 // [1024,1024,3] f32
  dim3 grid(WW / TSX, HH / TSY);              // 64 x 128 = 8192 blocks
  dim3 block(128);
  denoiser_kpn<<<grid, block, 0, stream>>>(unet, cnn, out);
}

// Round 16
// 73.038 us; speedup vs baseline: 1.5148x; 1.0481x over previous
//
#include <hip/hip_runtime.h>

#define HH 1024
#define WW 1024
#define KK 9
#define PADK 4
#define TSX 16
#define TSY 8
#define NPX 128    // pixels per block
#define TROWS 16   // TSY + 2*PADK
#define TCOLS 24   // TSX + 2*PADK
#define NW 81
#define ROWB 5184  // 16 px * 324 B, contiguous per image row
#define AUXNT 2    // streaming/NT cache policy for stream-once cnn reads

#define GLDS(src, dst, w, aux)                                         \
  __builtin_amdgcn_global_load_lds(                                    \
      (const __attribute__((address_space(1))) unsigned int*)(src),    \
      (__attribute__((address_space(3))) unsigned int*)(dst), w, 0, aux)

// R12 (best: 71.3 us) + two cache-path levers, nothing else changed:
// (1) NT hint on weight DMA: cnn is 340 MB stream-once; keep it from
//     evicting unet lines so tile reads stay L2/L3-hit.
// (2) Bijective XCD slab swizzle (8192 = 8 XCD x 1024): each XCD's L2 sees
//     a contiguous 16-row image slab -> unet slab (~1.6 MB) L2-resident,
//     y-adjacent halo rows become L2-hits instead of L3/HBM.
__global__ __launch_bounds__(128) void denoiser_kpn(
    const float* __restrict__ unet, const float* __restrict__ cnn,
    float* __restrict__ out) {
  __shared__ __attribute__((aligned(16))) float wlds[NPX * NW];  // 41472 B
  __shared__ float4 tile[TROWS][TCOLS + 1];                      // 6400 B

  // XCD slab swizzle: hw XCD = bid % 8; give XCD k tiles [k*1024, (k+1)*1024).
  const int bid = blockIdx.x;
  const int nb = (bid & 7) * 1024 + (bid >> 3);
  const int bx = nb & 63;   // 64 x-tiles (fastest within a slab row-run)
  const int by = nb >> 6;   // 128 y-tiles; slab = 16 consecutive by per XCD
  const int px0 = bx * TSX;
  const int py0 = by * TSY;

  const int tid = threadIdx.x;   // 0..127
  const int lane = tid & 63;
  const int wv = tid >> 6;       // wave 0/1
  const int tx = tid & 15;
  const int ty = tid >> 4;       // 0..7

  // ---- 1. Tile global loads first (oldest VMEM): 384 entries / 128 thr. ----
  float tr_[3][3];
#pragma unroll
  for (int i = 0; i < 3; ++i) {
    const int idx = tid + 128 * i;        // 0..383 over 16x24
    const int r = idx / TCOLS;
    const int c = idx - r * TCOLS;
    int gy = py0 - PADK + r;
    gy = gy < 0 ? -gy : (gy >= HH ? 2 * HH - 2 - gy : gy);
    int gx = px0 - PADK + c;
    gx = gx < 0 ? -gx : (gx >= WW ? 2 * WW - 2 - gx : gx);
    __builtin_memcpy(&tr_[i][0], unet + ((size_t)gy * WW + gx) * 3, 12);
  }
  __builtin_amdgcn_sched_barrier(0);

  // ---- 2. Weight DMA (NT): wave wv stages its own rows 4wv..4wv+3. ----
#pragma unroll
  for (int rr = 0; rr < 4; ++rr) {
    const int r = wv * 4 + rr;
    const char* s = (const char*)(cnn + ((size_t)(py0 + r) * WW + px0) * NW);
    char* d = (char*)wlds + r * ROWB;
#pragma unroll
    for (int i = 0; i < 5; ++i)
      GLDS(s + i * 1024 + lane * 16, d + i * 1024 + lane * 16, 16, AUXNT);
    if (lane < 16) GLDS(s + 5120 + lane * 4, d + 5120 + lane * 4, 4, AUXNT);
  }
  __builtin_amdgcn_sched_barrier(0);

  // ---- 3. Tile -> LDS (compiler waits only the 3 tile loads: vmcnt(24)). --
#pragma unroll
  for (int i = 0; i < 3; ++i) {
    const int idx = tid + 128 * i;
    const int r = idx / TCOLS;
    const int c = idx - r * TCOLS;
    tile[r][c] = make_float4(tr_[i][0], tr_[i][1], tr_[i][2], 0.0f);
  }
  __builtin_amdgcn_sched_barrier(0);
  asm volatile("s_waitcnt lgkmcnt(0)" ::: "memory");
  __builtin_amdgcn_s_barrier();  // publish tile; weight DMA stays in flight
  __builtin_amdgcn_sched_barrier(0);
  asm volatile("s_waitcnt vmcnt(0)" ::: "memory");  // own rows' weights landed
  __builtin_amdgcn_sched_barrier(0);

  // ---- 4. 81 taps: tile b128 free of conflicts ((ty+tx) mod 8 spread),
  //         weight b32 lane-stride 81 dwords -> 2-way = free. ----
  float ax = 0.0f, ay = 0.0f, az = 0.0f;
  const float* wrow = wlds + tid * NW;
#pragma unroll
  for (int ki = 0; ki < KK; ++ki)
#pragma unroll
    for (int kj = 0; kj < KK; ++kj) {
      const float4 pv = tile[ty + ki][tx + kj];
      const float w = wrow[ki * KK + kj];
      ax = fmaf(w, pv.x, ax);
      ay = fmaf(w, pv.y, ay);
      az = fmaf(w, pv.z, az);
    }

  const float o[3] = {ax, ay, az};
  __builtin_memcpy(out + ((size_t)(py0 + ty) * WW + px0 + tx) * 3, &o[0], 12);
}

extern "C" void kernel_launch(void* const* d_in, const int* in_sizes, int n_in,
                              void* d_out, int out_size, void* d_ws, size_t ws_size,
                              hipStream_t stream) {
  const float* unet = (const float*)d_in[0];  // [1024,1024,3] f32
  const float* cnn = (const float*)d_in[1];   // [1024,1024,81] f32
  float* out = (float*)d_out;                 // [1024,1024,3] f32
  denoiser_kpn<<<dim3(8192), dim3(NPX), 0, stream>>>(unet, cnn, out);
}